// Round 10
// baseline (57.029 us; speedup 1.0000x reference)
//
#include <hip/hip_runtime.h>
#include <math.h>

#define B_ 2
#define N_ 512
#define C_ 32
#define H_ 200
#define W_ 200
#define HW_ (H_*W_)
#define THRESH_ 0.05f
#define OUT_BEV (B_*C_*H_*W_)
#define NSEG 4                    // 4 waves/block, 128 gaussians each
#define TILES_PER_B 625           // 25x25 tiles of 8x8
#define LOG2E 1.4426950408889634f
#define LN2   0.6931471805599453f
#define REPS 7                    // DIAGNOSTIC: amplify warm body to surface counters

typedef float v2f __attribute__((ext_vector_type(2)));

__device__ __forceinline__ float rlane(float x, int l) {
    return __int_as_float(__builtin_amdgcn_readlane(__float_as_int(x), l));
}

// Per-lane gaussian param compute + exact-ellipse-bbox tile-overlap test.
__device__ __forceinline__ bool pcompute(
    const float* __restrict__ m3, const float* __restrict__ cv,
    const float* __restrict__ opc, int i,
    float tu0, float tu1, float tv0, float tv1,
    float& mu_u, float& mu_v, float& a2, float& b2, float& c2,
    float& opo, float& thr2)
{
    float x  = m3[i*3 + 0];
    float y  = m3[i*3 + 1];
    float c0 = cv[i*6 + 0];
    float c1 = cv[i*6 + 1];
    float c3 = cv[i*6 + 3];
    float op = opc[i];
    mu_u = 100.0f - 100.0f * y;
    mu_v = 100.0f - 100.0f * x;
    float Cuu = 10000.0f * c3 + 0.3f;
    float Cvv = 10000.0f * c0 + 0.3f;
    float Cuv = 10000.0f * c1;
    float det = Cuu * Cvv - Cuv * Cuv;
    bool valid = det > 0.0f;
    float opac = (op > THRESH_) ? op : 0.0f;
    if (!valid) opac = 0.0f;
    float inv_det = valid ? (1.0f / det) : 0.0f;
    a2 = -0.5f * LOG2E * (Cvv * inv_det);
    b2 = -0.5f * LOG2E * (Cuu * inv_det);
    c2 =  LOG2E * (Cuv * inv_det);
    opo = opac;
    if (opac > 0.0f) {
        float r2 = log2f(255.0f * opac);          // > 0 since opac > 0.05
        thr2 = -r2;
        float rn = LN2 * r2;
        float du_max = sqrtf(fmaxf(2.0f * rn * Cuu, 0.0f)) + 1.0e-3f;
        float dv_max = sqrtf(fmaxf(2.0f * rn * Cvv, 0.0f)) + 1.0e-3f;
        return (mu_u - du_max <= tu1) & (mu_u + du_max >= tu0) &
               (mu_v - dv_max <= tv1) & (mu_v + dv_max >= tv0);
    }
    thr2 = 3.0e38f;
    return false;
}

// Walk a 64-bit hit mask two gaussians at a time (ctz ascending = order
// preserved). Params broadcast via readlane; feature rows wave-uniform ->
// s_load; pk-FMA accumulation.
#define WALK(mask, P, base_n)                                                \
    while (mask) {                                                           \
        int j0 = __builtin_ctzll(mask); mask &= mask - 1;                    \
        bool two = (mask != 0ull);                                           \
        int j1 = two ? __builtin_ctzll(mask) : j0;                           \
        if (two) mask &= mask - 1;                                           \
        float mu_u0 = rlane(P##_mu_u, j0), mu_v0 = rlane(P##_mu_v, j0);      \
        float a0 = rlane(P##_a, j0), b0 = rlane(P##_b, j0);                  \
        float c0 = rlane(P##_c, j0), op0 = rlane(P##_op, j0);                \
        float th0 = rlane(P##_th, j0);                                       \
        float mu_u1 = rlane(P##_mu_u, j1), mu_v1 = rlane(P##_mu_v, j1);      \
        float a1 = rlane(P##_a, j1), b1 = rlane(P##_b, j1);                  \
        float c1 = rlane(P##_c, j1), op1 = rlane(P##_op, j1);                \
        float th1 = rlane(P##_th, j1);                                       \
        const v2f* f0 = (const v2f*)(featB + (size_t)((base_n) + j0) * C_);  \
        const v2f* f1 = (const v2f*)(featB + (size_t)((base_n) + j1) * C_);  \
        float du0 = u - mu_u0, dv0 = v - mu_v0;                              \
        float pw0 = fmaf(a0 * du0, du0, fmaf(b0 * dv0, dv0, c0 * (du0 * dv0))); \
        bool hit0 = (pw0 <= 0.0f) && (pw0 >= th0);                           \
        float al0 = hit0 ? fminf(0.99f, op0 * exp2f(pw0)) : 0.0f;            \
        float du1 = u - mu_u1, dv1 = v - mu_v1;                              \
        float pw1 = fmaf(a1 * du1, du1, fmaf(b1 * dv1, dv1, c1 * (du1 * dv1))); \
        bool hit1 = two && (pw1 <= 0.0f) && (pw1 >= th1);                    \
        float al1 = hit1 ? fminf(0.99f, op1 * exp2f(pw1)) : 0.0f;            \
        if (__any(hit0 | hit1)) {                                            \
            float w0 = T * al0;                                              \
            float Tm = T * (1.0f - al0);                                     \
            float w1 = Tm * al1;                                             \
            T = Tm * (1.0f - al1);                                           \
            v2f w0v = {w0, w0}, w1v = {w1, w1};                              \
            _Pragma("unroll")                                                \
            for (int i = 0; i < 16; ++i)                                     \
                acc2[i] = __builtin_elementwise_fma(w1v, f1[i],              \
                          __builtin_elementwise_fma(w0v, f0[i], acc2[i]));   \
        }                                                                    \
    }

// R9 structure exactly, body repeated REPS times (identical work + stores;
// final rep leaves correct output). Blocks 0..1249: one 8x8 tile.
// Block 1250: num_gaussians scalar.
__global__ __launch_bounds__(256, 5) void render_kernel(
    const float* __restrict__ features,   // [B,N,C]
    const float* __restrict__ means3D,    // [B,N,3]
    const float* __restrict__ cov3D,      // [B,N,6]
    const float* __restrict__ opacities,  // [B,N,1]
    float* __restrict__ out)              // [B,C,H,W] + 1 scalar
{
    __shared__ float s_T[NSEG][64];                 // 1 KB
    __shared__ unsigned int s_pk[NSEG * 16 * 64];   // 16 KB: bf16x2 partials

    int blk = blockIdx.x;
    int tid = threadIdx.x;

    if (blk == B_ * TILES_PER_B) {           // ---- count-only block ----
        for (int rep = 0; rep < REPS; ++rep) {
            int cnt = ((opacities[tid]       > THRESH_) ? 1 : 0)
                    + ((opacities[tid + 256] > THRESH_) ? 1 : 0)
                    + ((opacities[tid + 512] > THRESH_) ? 1 : 0)
                    + ((opacities[tid + 768] > THRESH_) ? 1 : 0);
            for (int off = 32; off > 0; off >>= 1) cnt += __shfl_down(cnt, off);
            int* s_red = (int*)s_T;
            if ((tid & 63) == 0) s_red[tid >> 6] = cnt;
            __syncthreads();
            if (tid == 0)
                out[OUT_BEV] = (float)(s_red[0] + s_red[1] + s_red[2] + s_red[3]) * 0.5f;
            __syncthreads();
        }
        return;
    }

    int b  = blk / TILES_PER_B;
    int t  = blk - b * TILES_PER_B;
    int tu = t / 25;
    int tv = t - tu * 25;
    int wave = __builtin_amdgcn_readfirstlane(tid >> 6);   // uniform
    int lane = tid & 63;

    float tu0 = (float)(tu * 8), tu1 = tu0 + 7.0f;
    float tv0 = (float)(tv * 8), tv1 = tv0 + 7.0f;

    for (int rep = 0; rep < REPS; ++rep) {
        // ---- per-lane params for the wave's two 64-gaussian halves ----
        float A_mu_u, A_mu_v, A_a, A_b, A_c, A_op, A_th;
        float B_mu_u, B_mu_v, B_a, B_b, B_c, B_op, B_th;
        int i0 = b * N_ + wave * 128 + lane;
        bool ovA = pcompute(means3D, cov3D, opacities, i0,      tu0, tu1, tv0, tv1,
                            A_mu_u, A_mu_v, A_a, A_b, A_c, A_op, A_th);
        bool ovB = pcompute(means3D, cov3D, opacities, i0 + 64, tu0, tu1, tv0, tv1,
                            B_mu_u, B_mu_v, B_a, B_b, B_c, B_op, B_th);
        unsigned long long m0 = __ballot(ovA);
        unsigned long long m1 = __ballot(ovB);

        int uu = tu * 8 + (lane >> 3);
        int vv = tv * 8 + (lane & 7);
        float u = (float)uu, v = (float)vv;

        float T = 1.0f;
        v2f acc2[16];
#pragma unroll
        for (int i = 0; i < 16; ++i) acc2[i] = (v2f){0.0f, 0.0f};
        const float* featB = features + (size_t)b * (N_ * C_);

        // ---- ordered hit loops: two 64-gaussian halves of this segment ----
        WALK(m0, A, wave * 128)
        WALK(m1, B, wave * 128 + 64)

        // ---- single-barrier combine: bf16-pack, stage, sync, reduce ----
        s_T[wave][lane] = T;
#pragma unroll
        for (int i = 0; i < 16; ++i) {
            unsigned int r;
            asm("v_cvt_pk_bf16_f32 %0, %1, %2"
                : "=v"(r) : "v"(acc2[i].x), "v"(acc2[i].y));
            s_pk[(wave * 16 + i) * 64 + lane] = r;
        }
        __syncthreads();

        float t0g = s_T[0][lane], t1g = s_T[1][lane], t2g = s_T[2][lane];
        float Wg[NSEG];
        Wg[0] = 1.0f;
        Wg[1] = t0g;
        Wg[2] = t0g * t1g;
        Wg[3] = Wg[2] * t2g;

        size_t obase = (size_t)b * C_ * HW_ + (size_t)(tu * 8) * W_ + (size_t)(tv * 8);
        size_t opix  = (size_t)(lane >> 3) * W_ + (lane & 7);
#pragma unroll
        for (int q = 0; q < 4; ++q) {
            int pr = wave * 4 + q;
            float vlo = 0.0f, vhi = 0.0f;
#pragma unroll
            for (int g = 0; g < NSEG; ++g) {
                unsigned int r = s_pk[(g * 16 + pr) * 64 + lane];
                float flo = __uint_as_float(r << 16);
                float fhi = __uint_as_float(r & 0xffff0000u);
                vlo = fmaf(Wg[g], flo, vlo);
                vhi = fmaf(Wg[g], fhi, vhi);
            }
            out[obase + (size_t)(2 * pr)     * HW_ + opix] = vlo;
            out[obase + (size_t)(2 * pr + 1) * HW_ + opix] = vhi;
        }
        __syncthreads();   // rep r reads done before rep r+1 rewrites s_pk/s_T
    }
}

extern "C" void kernel_launch(void* const* d_in, const int* in_sizes, int n_in,
                              void* d_out, int out_size, void* d_ws, size_t ws_size,
                              hipStream_t stream) {
    const float* features  = (const float*)d_in[0];
    const float* means3D   = (const float*)d_in[1];
    const float* cov3D     = (const float*)d_in[2];
    const float* opacities = (const float*)d_in[3];
    float* out = (float*)d_out;
    render_kernel<<<B_ * TILES_PER_B + 1, 256, 0, stream>>>(
        features, means3D, cov3D, opacities, out);
}

// Round 11
// 42.910 us; speedup vs baseline: 1.3290x; 1.3290x over previous
//
#include <hip/hip_runtime.h>
#include <math.h>

#define B_ 2
#define N_ 512
#define C_ 32
#define H_ 200
#define W_ 200
#define HW_ (H_*W_)
#define THRESH_ 0.05f
#define OUT_BEV (B_*C_*H_*W_)
#define NSEG 4                    // 4 waves/block, 128 gaussians each
#define TILES_PER_B 625           // 25x25 tiles of 8x8
#define NTILES (B_*TILES_PER_B)   // 1250
#define PERSIST 1024              // persistent render blocks (4 per CU)
#define LOG2E 1.4426950408889634f
#define LN2   0.6931471805599453f

typedef float v2f __attribute__((ext_vector_type(2)));

__device__ __forceinline__ float rlane(float x, int l) {
    return __int_as_float(__builtin_amdgcn_readlane(__float_as_int(x), l));
}

// Per-lane gaussian params + exact-ellipse bbox extents (tile-independent).
// Empty bbox encoded as negative extents.
__device__ __forceinline__ void pcompute(
    const float* __restrict__ m3, const float* __restrict__ cv,
    const float* __restrict__ opc, int i,
    float& mu_u, float& mu_v, float& a2, float& b2, float& c2,
    float& opo, float& thr2, float& dum, float& dvm)
{
    float x  = m3[i*3 + 0];
    float y  = m3[i*3 + 1];
    float c0 = cv[i*6 + 0];
    float c1 = cv[i*6 + 1];
    float c3 = cv[i*6 + 3];
    float op = opc[i];
    mu_u = 100.0f - 100.0f * y;
    mu_v = 100.0f - 100.0f * x;
    float Cuu = 10000.0f * c3 + 0.3f;
    float Cvv = 10000.0f * c0 + 0.3f;
    float Cuv = 10000.0f * c1;
    float det = Cuu * Cvv - Cuv * Cuv;
    bool valid = det > 0.0f;
    float opac = (op > THRESH_) ? op : 0.0f;
    if (!valid) opac = 0.0f;
    float inv_det = valid ? (1.0f / det) : 0.0f;
    a2 = -0.5f * LOG2E * (Cvv * inv_det);
    b2 = -0.5f * LOG2E * (Cuu * inv_det);
    c2 =  LOG2E * (Cuv * inv_det);
    opo = opac;
    if (opac > 0.0f) {
        float r2 = log2f(255.0f * opac);          // > 0 since opac > 0.05
        thr2 = -r2;
        float rn = LN2 * r2;
        dum = sqrtf(fmaxf(2.0f * rn * Cuu, 0.0f)) + 1.0e-3f;
        dvm = sqrtf(fmaxf(2.0f * rn * Cvv, 0.0f)) + 1.0e-3f;
    } else {
        thr2 = 3.0e38f;
        dum = -1.0e30f;
        dvm = -1.0e30f;
    }
}

// Walk a 64-bit hit mask two gaussians at a time (ctz ascending = order
// preserved). Params broadcast via readlane (SGPRs); feature rows
// wave-uniform -> s_load; pk-FMA accumulation.
#define WALK(mask, P, base_n)                                                \
    while (mask) {                                                           \
        int j0 = __builtin_ctzll(mask); mask &= mask - 1;                    \
        bool two = (mask != 0ull);                                           \
        int j1 = two ? __builtin_ctzll(mask) : j0;                           \
        if (two) mask &= mask - 1;                                           \
        float mu_u0 = rlane(P##_mu_u, j0), mu_v0 = rlane(P##_mu_v, j0);      \
        float a0 = rlane(P##_a, j0), b0 = rlane(P##_b, j0);                  \
        float c0 = rlane(P##_c, j0), op0 = rlane(P##_op, j0);                \
        float th0 = rlane(P##_th, j0);                                       \
        float mu_u1 = rlane(P##_mu_u, j1), mu_v1 = rlane(P##_mu_v, j1);      \
        float a1 = rlane(P##_a, j1), b1 = rlane(P##_b, j1);                  \
        float c1 = rlane(P##_c, j1), op1 = rlane(P##_op, j1);                \
        float th1 = rlane(P##_th, j1);                                       \
        const v2f* f0 = (const v2f*)(featB + (size_t)((base_n) + j0) * C_);  \
        const v2f* f1 = (const v2f*)(featB + (size_t)((base_n) + j1) * C_);  \
        float du0 = u - mu_u0, dv0 = v - mu_v0;                              \
        float pw0 = fmaf(a0 * du0, du0, fmaf(b0 * dv0, dv0, c0 * (du0 * dv0))); \
        bool hit0 = (pw0 <= 0.0f) && (pw0 >= th0);                           \
        float al0 = hit0 ? fminf(0.99f, op0 * exp2f(pw0)) : 0.0f;            \
        float du1 = u - mu_u1, dv1 = v - mu_v1;                              \
        float pw1 = fmaf(a1 * du1, du1, fmaf(b1 * dv1, dv1, c1 * (du1 * dv1))); \
        bool hit1 = two && (pw1 <= 0.0f) && (pw1 >= th1);                    \
        float al1 = hit1 ? fminf(0.99f, op1 * exp2f(pw1)) : 0.0f;            \
        if (__any(hit0 | hit1)) {                                            \
            float w0 = T * al0;                                              \
            float Tm = T * (1.0f - al0);                                     \
            float w1 = Tm * al1;                                             \
            T = Tm * (1.0f - al1);                                           \
            v2f w0v = {w0, w0}, w1v = {w1, w1};                              \
            _Pragma("unroll")                                                \
            for (int i = 0; i < 16; ++i)                                     \
                acc2[i] = __builtin_elementwise_fma(w1v, f1[i],              \
                          __builtin_elementwise_fma(w0v, f0[i], acc2[i]));   \
        }                                                                    \
    }

// Persistent blocks pull tiles from an atomic ticket queue (counter != null);
// params cached in registers across tiles of the same batch. Last block:
// num_gaussians scalar. Static fallback (counter == null): tile = blockIdx.
__global__ __launch_bounds__(256, 4) void render_kernel(
    const float* __restrict__ features,   // [B,N,C]
    const float* __restrict__ means3D,    // [B,N,3]
    const float* __restrict__ cov3D,      // [B,N,6]
    const float* __restrict__ opacities,  // [B,N,1]
    float* __restrict__ out,              // [B,C,H,W] + 1 scalar
    unsigned int* __restrict__ counter)   // d_ws ticket counter (or null)
{
    __shared__ float s_T[NSEG][64];                 // 1 KB
    __shared__ unsigned int s_pk[NSEG * 16 * 64];   // 16 KB bf16x2 partials
    __shared__ int s_ticket;

    int tid = threadIdx.x;

    if (blockIdx.x == gridDim.x - 1) {       // ---- count-only block ----
        int cnt = ((opacities[tid]       > THRESH_) ? 1 : 0)
                + ((opacities[tid + 256] > THRESH_) ? 1 : 0)
                + ((opacities[tid + 512] > THRESH_) ? 1 : 0)
                + ((opacities[tid + 768] > THRESH_) ? 1 : 0);
        for (int off = 32; off > 0; off >>= 1) cnt += __shfl_down(cnt, off);
        int* s_red = (int*)s_T;
        if ((tid & 63) == 0) s_red[tid >> 6] = cnt;
        __syncthreads();
        if (tid == 0)
            out[OUT_BEV] = (float)(s_red[0] + s_red[1] + s_red[2] + s_red[3]) * 0.5f;
        return;
    }

    int wave = __builtin_amdgcn_readfirstlane(tid >> 6);   // uniform
    int lane = tid & 63;

    // register-cached per-batch params (lane owns gaussians i0, i0+64)
    int b_cur = -1;
    float A_mu_u, A_mu_v, A_a, A_b, A_c, A_op, A_th, A_dum, A_dvm;
    float B_mu_u, B_mu_v, B_a, B_b, B_c, B_op, B_th, B_dum, B_dvm;
    const float* featB = features;

    for (;;) {
        int t;
        if (counter) {
            if (tid == 0) s_ticket = (int)atomicAdd(counter, 1u);
            __syncthreads();
            t = s_ticket;
            if (t >= NTILES) break;
        } else {
            t = blockIdx.x;
        }

        int b  = t / TILES_PER_B;
        int tt = t - b * TILES_PER_B;
        int tu = tt / 25;
        int tv = tt - tu * 25;

        if (b != b_cur) {                    // block-uniform branch
            int i0 = b * N_ + wave * 128 + lane;
            pcompute(means3D, cov3D, opacities, i0,
                     A_mu_u, A_mu_v, A_a, A_b, A_c, A_op, A_th, A_dum, A_dvm);
            pcompute(means3D, cov3D, opacities, i0 + 64,
                     B_mu_u, B_mu_v, B_a, B_b, B_c, B_op, B_th, B_dum, B_dvm);
            featB = features + (size_t)b * (N_ * C_);
            b_cur = b;
        }

        float tu0 = (float)(tu * 8), tu1 = tu0 + 7.0f;
        float tv0 = (float)(tv * 8), tv1 = tv0 + 7.0f;

        bool ovA = (A_mu_u - A_dum <= tu1) & (A_mu_u + A_dum >= tu0) &
                   (A_mu_v - A_dvm <= tv1) & (A_mu_v + A_dvm >= tv0);
        bool ovB = (B_mu_u - B_dum <= tu1) & (B_mu_u + B_dum >= tu0) &
                   (B_mu_v - B_dvm <= tv1) & (B_mu_v + B_dvm >= tv0);
        unsigned long long m0 = __ballot(ovA);
        unsigned long long m1 = __ballot(ovB);

        int uu = tu * 8 + (lane >> 3);
        int vv = tv * 8 + (lane & 7);
        float u = (float)uu, v = (float)vv;

        float T = 1.0f;
        v2f acc2[16];
#pragma unroll
        for (int i = 0; i < 16; ++i) acc2[i] = (v2f){0.0f, 0.0f};

        // ---- ordered hit loops: two 64-gaussian halves of this segment ----
        WALK(m0, A, wave * 128)
        WALK(m1, B, wave * 128 + 64)

        // ---- single-barrier combine: bf16-pack, stage, sync, reduce ----
        s_T[wave][lane] = T;
#pragma unroll
        for (int i = 0; i < 16; ++i) {
            unsigned int r;
            asm("v_cvt_pk_bf16_f32 %0, %1, %2"
                : "=v"(r) : "v"(acc2[i].x), "v"(acc2[i].y));
            s_pk[(wave * 16 + i) * 64 + lane] = r;
        }
        __syncthreads();

        float t0g = s_T[0][lane], t1g = s_T[1][lane], t2g = s_T[2][lane];
        float Wg[NSEG];
        Wg[0] = 1.0f;
        Wg[1] = t0g;
        Wg[2] = t0g * t1g;
        Wg[3] = Wg[2] * t2g;

        size_t obase = (size_t)b * C_ * HW_ + (size_t)(tu * 8) * W_ + (size_t)(tv * 8);
        size_t opix  = (size_t)(lane >> 3) * W_ + (lane & 7);
#pragma unroll
        for (int q = 0; q < 4; ++q) {
            int pr = wave * 4 + q;
            float vlo = 0.0f, vhi = 0.0f;
#pragma unroll
            for (int g = 0; g < NSEG; ++g) {
                unsigned int r = s_pk[(g * 16 + pr) * 64 + lane];
                float flo = __uint_as_float(r << 16);
                float fhi = __uint_as_float(r & 0xffff0000u);
                vlo = fmaf(Wg[g], flo, vlo);
                vhi = fmaf(Wg[g], fhi, vhi);
            }
            out[obase + (size_t)(2 * pr)     * HW_ + opix] = vlo;
            out[obase + (size_t)(2 * pr + 1) * HW_ + opix] = vhi;
        }
        __syncthreads();      // protects s_pk/s_T/s_ticket before next tile
        if (!counter) break;  // static mode: one tile per block
    }
}

extern "C" void kernel_launch(void* const* d_in, const int* in_sizes, int n_in,
                              void* d_out, int out_size, void* d_ws, size_t ws_size,
                              hipStream_t stream) {
    const float* features  = (const float*)d_in[0];
    const float* means3D   = (const float*)d_in[1];
    const float* cov3D     = (const float*)d_in[2];
    const float* opacities = (const float*)d_in[3];
    float* out = (float*)d_out;

    bool dyn = (ws_size >= sizeof(unsigned int));
    unsigned int* counter = dyn ? (unsigned int*)d_ws : nullptr;
    if (dyn) hipMemsetAsync(d_ws, 0, sizeof(unsigned int), stream);

    int nblocks = dyn ? (PERSIST + 1) : (NTILES + 1);
    render_kernel<<<nblocks, 256, 0, stream>>>(
        features, means3D, cov3D, opacities, out, counter);
}

// Round 12
// 16.484 us; speedup vs baseline: 3.4596x; 2.6031x over previous
//
#include <hip/hip_runtime.h>
#include <math.h>

#define B_ 2
#define N_ 512
#define C_ 32
#define H_ 200
#define W_ 200
#define HW_ (H_*W_)
#define THRESH_ 0.05f
#define OUT_BEV (B_*C_*H_*W_)
#define NSEG 4                    // 4 waves/block, 128 gaussians each
#define TILES_PER_B 625           // 25x25 tiles of 8x8
#define LOG2E 1.4426950408889634f
#define LN2   0.6931471805599453f

typedef float v2f __attribute__((ext_vector_type(2)));

__device__ __forceinline__ float rlane(float x, int l) {
    return __int_as_float(__builtin_amdgcn_readlane(__float_as_int(x), l));
}

// Per-lane gaussian params (log2-domain quadratic). inv2a=1/(2a2), inv2b=1/(2b2).
__device__ __forceinline__ void pcompute(
    const float* __restrict__ m3, const float* __restrict__ cv,
    const float* __restrict__ opc, int i,
    float& mu_u, float& mu_v, float& a2, float& b2, float& c2,
    float& opo, float& thr2, float& inv2a, float& inv2b)
{
    float x  = m3[i*3 + 0];
    float y  = m3[i*3 + 1];
    float c0 = cv[i*6 + 0];
    float c1 = cv[i*6 + 1];
    float c3 = cv[i*6 + 3];
    float op = opc[i];
    mu_u = 100.0f - 100.0f * y;
    mu_v = 100.0f - 100.0f * x;
    float Cuu = 10000.0f * c3 + 0.3f;
    float Cvv = 10000.0f * c0 + 0.3f;
    float Cuv = 10000.0f * c1;
    float det = Cuu * Cvv - Cuv * Cuv;
    bool valid = det > 0.0f;
    float opac = (op > THRESH_) ? op : 0.0f;
    if (!valid) opac = 0.0f;
    float inv_det = valid ? (1.0f / det) : 0.0f;
    a2 = -0.5f * LOG2E * (Cvv * inv_det);
    b2 = -0.5f * LOG2E * (Cuu * inv_det);
    c2 =  LOG2E * (Cuv * inv_det);
    opo = opac;
    if (opac > 0.0f) {
        thr2 = -log2f(255.0f * opac);             // < 0 since opac > 0.05
        inv2a = 1.0f / (2.0f * a2);               // a2,b2 < 0 strictly (PD cov)
        inv2b = 1.0f / (2.0f * b2);
    } else {
        thr2 = 3.0e38f;
        inv2a = 0.0f;
        inv2b = 0.0f;
    }
}

// Max of pw over edge u=due (dv in [dvlo,dvhi]) of the concave quadratic.
__device__ __forceinline__ float edge_max_u(float a2, float b2, float c2,
                                            float due, float dvlo, float dvhi,
                                            float inv2b) {
    float dvs = fminf(fmaxf(-c2 * due * inv2b, dvlo), dvhi);
    return fmaf(a2 * due, due, fmaf(b2 * dvs, dvs, c2 * (due * dvs)));
}
__device__ __forceinline__ float edge_max_v(float a2, float b2, float c2,
                                            float dve, float dulo, float duhi,
                                            float inv2a) {
    float dus = fminf(fmaxf(-c2 * dve * inv2a, dulo), duhi);
    return fmaf(a2 * dus, dus, fmaf(b2 * dve, dve, c2 * (dus * dve)));
}

// Exact ellipse-vs-tile test: keep iff max_{rect} pw >= thr2 (conservative-safe).
#define OVTEST(P, ovname)                                                     \
    bool ovname;                                                              \
    {                                                                         \
        float dulo = tu0 - P##_mu_u, duhi = tu1 - P##_mu_u;                   \
        float dvlo = tv0 - P##_mu_v, dvhi = tv1 - P##_mu_v;                   \
        bool inside = (dulo <= 0.0f) & (duhi >= 0.0f) &                       \
                      (dvlo <= 0.0f) & (dvhi >= 0.0f);                        \
        float e0 = edge_max_u(P##_a, P##_b, P##_c, dulo, dvlo, dvhi, P##_i2b);\
        float e1 = edge_max_u(P##_a, P##_b, P##_c, duhi, dvlo, dvhi, P##_i2b);\
        float e2 = edge_max_v(P##_a, P##_b, P##_c, dvlo, dulo, duhi, P##_i2a);\
        float e3 = edge_max_v(P##_a, P##_b, P##_c, dvhi, dulo, duhi, P##_i2a);\
        float mx = fmaxf(fmaxf(e0, e1), fmaxf(e2, e3));                       \
        ovname = (P##_op > 0.0f) && (inside || (mx >= P##_th));               \
    }

// Walk a 64-bit hit mask two gaussians at a time (ctz ascending = order
// preserved). Params broadcast via readlane; feature rows wave-uniform ->
// s_load; pk-FMA accumulation.
#define WALK(mask, P, base_n)                                                \
    while (mask) {                                                           \
        int j0 = __builtin_ctzll(mask); mask &= mask - 1;                    \
        bool two = (mask != 0ull);                                           \
        int j1 = two ? __builtin_ctzll(mask) : j0;                           \
        if (two) mask &= mask - 1;                                           \
        float mu_u0 = rlane(P##_mu_u, j0), mu_v0 = rlane(P##_mu_v, j0);      \
        float a0 = rlane(P##_a, j0), b0 = rlane(P##_b, j0);                  \
        float c0 = rlane(P##_c, j0), op0 = rlane(P##_op, j0);                \
        float th0 = rlane(P##_th, j0);                                       \
        float mu_u1 = rlane(P##_mu_u, j1), mu_v1 = rlane(P##_mu_v, j1);      \
        float a1 = rlane(P##_a, j1), b1 = rlane(P##_b, j1);                  \
        float c1 = rlane(P##_c, j1), op1 = rlane(P##_op, j1);                \
        float th1 = rlane(P##_th, j1);                                       \
        const v2f* f0 = (const v2f*)(featB + (size_t)((base_n) + j0) * C_);  \
        const v2f* f1 = (const v2f*)(featB + (size_t)((base_n) + j1) * C_);  \
        float du0 = u - mu_u0, dv0 = v - mu_v0;                              \
        float pw0 = fmaf(a0 * du0, du0, fmaf(b0 * dv0, dv0, c0 * (du0 * dv0))); \
        bool hit0 = (pw0 <= 0.0f) && (pw0 >= th0);                           \
        float al0 = hit0 ? fminf(0.99f, op0 * exp2f(pw0)) : 0.0f;            \
        float du1 = u - mu_u1, dv1 = v - mu_v1;                              \
        float pw1 = fmaf(a1 * du1, du1, fmaf(b1 * dv1, dv1, c1 * (du1 * dv1))); \
        bool hit1 = two && (pw1 <= 0.0f) && (pw1 >= th1);                    \
        float al1 = hit1 ? fminf(0.99f, op1 * exp2f(pw1)) : 0.0f;            \
        if (__any(hit0 | hit1)) {                                            \
            float w0 = T * al0;                                              \
            float Tm = T * (1.0f - al0);                                     \
            float w1 = Tm * al1;                                             \
            T = Tm * (1.0f - al1);                                           \
            v2f w0v = {w0, w0}, w1v = {w1, w1};                              \
            _Pragma("unroll")                                                \
            for (int i = 0; i < 16; ++i)                                     \
                acc2[i] = __builtin_elementwise_fma(w1v, f1[i],              \
                          __builtin_elementwise_fma(w0v, f0[i], acc2[i]));   \
        }                                                                    \
    }

// Blocks 0..1249: one 8x8 tile each, assigned CENTER-OUT (LPT: heavy interior
// tiles dispatch first, light border tiles fill the drain tail). Batches
// interleaved. Block 1250: num_gaussians scalar.
__global__ __launch_bounds__(256, 5) void render_kernel(
    const float* __restrict__ features,   // [B,N,C]
    const float* __restrict__ means3D,    // [B,N,3]
    const float* __restrict__ cov3D,      // [B,N,6]
    const float* __restrict__ opacities,  // [B,N,1]
    float* __restrict__ out)              // [B,C,H,W] + 1 scalar
{
    __shared__ float s_T[NSEG][64];                 // 1 KB
    __shared__ unsigned int s_pk[NSEG * 16 * 64];   // 16 KB bf16x2 partials

    int blk = blockIdx.x;
    int tid = threadIdx.x;

    if (blk == B_ * TILES_PER_B) {           // ---- count-only block ----
        int cnt = ((opacities[tid]       > THRESH_) ? 1 : 0)
                + ((opacities[tid + 256] > THRESH_) ? 1 : 0)
                + ((opacities[tid + 512] > THRESH_) ? 1 : 0)
                + ((opacities[tid + 768] > THRESH_) ? 1 : 0);
        for (int off = 32; off > 0; off >>= 1) cnt += __shfl_down(cnt, off);
        int* s_red = (int*)s_T;
        if ((tid & 63) == 0) s_red[tid >> 6] = cnt;
        __syncthreads();
        if (tid == 0)
            out[OUT_BEV] = (float)(s_red[0] + s_red[1] + s_red[2] + s_red[3]) * 0.5f;
        return;
    }

    // ---- center-out (LPT) tile assignment; batches interleaved ----
    int b = blk & 1;
    int i = blk >> 1;                        // 0..624, ring index
    int s = (int)sqrtf((float)i);            // exact for perfect squares
    int r = (s + 1) >> 1;                    // Chebyshev ring of tile
    int tu, tv;
    if (r == 0) {
        tu = 12; tv = 12;
    } else {
        int base = (2 * r - 1) * (2 * r - 1);
        int p  = i - base;                   // 0..8r-1 along perimeter
        int tr = 2 * r;
        int side = p / tr;
        int off  = p - side * tr;
        if      (side == 0) { tu = 12 - r + off; tv = 12 - r; }
        else if (side == 1) { tu = 12 + r;       tv = 12 - r + off; }
        else if (side == 2) { tu = 12 + r - off; tv = 12 + r; }
        else                { tu = 12 - r;       tv = 12 + r - off; }
    }

    int wave = __builtin_amdgcn_readfirstlane(tid >> 6);   // uniform
    int lane = tid & 63;

    float tu0 = (float)(tu * 8), tu1 = tu0 + 7.0f;
    float tv0 = (float)(tv * 8), tv1 = tv0 + 7.0f;

    // ---- per-lane params for the wave's two 64-gaussian halves ----
    float A_mu_u, A_mu_v, A_a, A_b, A_c, A_op, A_th, A_i2a, A_i2b;
    float B_mu_u, B_mu_v, B_a, B_b, B_c, B_op, B_th, B_i2a, B_i2b;
    int i0 = b * N_ + wave * 128 + lane;
    pcompute(means3D, cov3D, opacities, i0,
             A_mu_u, A_mu_v, A_a, A_b, A_c, A_op, A_th, A_i2a, A_i2b);
    pcompute(means3D, cov3D, opacities, i0 + 64,
             B_mu_u, B_mu_v, B_a, B_b, B_c, B_op, B_th, B_i2a, B_i2b);

    // ---- exact ellipse-vs-tile cull ----
    OVTEST(A, ovA)
    OVTEST(B, ovB)
    unsigned long long m0 = __ballot(ovA);
    unsigned long long m1 = __ballot(ovB);

    int uu = tu * 8 + (lane >> 3);
    int vv = tv * 8 + (lane & 7);
    float u = (float)uu, v = (float)vv;

    float T = 1.0f;
    v2f acc2[16];
#pragma unroll
    for (int i2 = 0; i2 < 16; ++i2) acc2[i2] = (v2f){0.0f, 0.0f};
    const float* featB = features + (size_t)b * (N_ * C_);

    // ---- ordered hit loops: two 64-gaussian halves of this segment ----
    WALK(m0, A, wave * 128)
    WALK(m1, B, wave * 128 + 64)

    // ---- single-barrier combine: bf16-pack, stage, sync, reduce ----
    s_T[wave][lane] = T;
#pragma unroll
    for (int i2 = 0; i2 < 16; ++i2) {
        unsigned int rr;
        asm("v_cvt_pk_bf16_f32 %0, %1, %2"
            : "=v"(rr) : "v"(acc2[i2].x), "v"(acc2[i2].y));
        s_pk[(wave * 16 + i2) * 64 + lane] = rr;
    }
    __syncthreads();                       // the ONLY barrier

    float t0g = s_T[0][lane], t1g = s_T[1][lane], t2g = s_T[2][lane];
    float Wg[NSEG];
    Wg[0] = 1.0f;
    Wg[1] = t0g;
    Wg[2] = t0g * t1g;
    Wg[3] = Wg[2] * t2g;

    size_t obase = (size_t)b * C_ * HW_ + (size_t)(tu * 8) * W_ + (size_t)(tv * 8);
    size_t opix  = (size_t)(lane >> 3) * W_ + (lane & 7);
#pragma unroll
    for (int q = 0; q < 4; ++q) {
        int pr = wave * 4 + q;             // packed pair -> channels 2pr, 2pr+1
        float vlo = 0.0f, vhi = 0.0f;
#pragma unroll
        for (int g = 0; g < NSEG; ++g) {
            unsigned int rr = s_pk[(g * 16 + pr) * 64 + lane];
            float flo = __uint_as_float(rr << 16);
            float fhi = __uint_as_float(rr & 0xffff0000u);
            vlo = fmaf(Wg[g], flo, vlo);
            vhi = fmaf(Wg[g], fhi, vhi);
        }
        out[obase + (size_t)(2 * pr)     * HW_ + opix] = vlo;
        out[obase + (size_t)(2 * pr + 1) * HW_ + opix] = vhi;
    }
}

extern "C" void kernel_launch(void* const* d_in, const int* in_sizes, int n_in,
                              void* d_out, int out_size, void* d_ws, size_t ws_size,
                              hipStream_t stream) {
    const float* features  = (const float*)d_in[0];
    const float* means3D   = (const float*)d_in[1];
    const float* cov3D     = (const float*)d_in[2];
    const float* opacities = (const float*)d_in[3];
    float* out = (float*)d_out;
    render_kernel<<<B_ * TILES_PER_B + 1, 256, 0, stream>>>(
        features, means3D, cov3D, opacities, out);
}